// Round 1
// baseline (31680.365 us; speedup 1.0000x reference)
//
#include <hip/hip_runtime.h>
#include <hip/hip_bf16.h>
#include <cstdint>
#include <cstddef>

#define NA 50000
#define NP 100000
#define HH 256
#define LL 3

typedef __attribute__((ext_vector_type(8))) short short8;
typedef __attribute__((ext_vector_type(4))) float f32x4;

__device__ __forceinline__ float bf2f(unsigned int u16) {
    unsigned int x = u16 << 16;
    return __builtin_bit_cast(float, x);
}
__device__ __forceinline__ unsigned short f2bf(float f) {
    __hip_bfloat16 h = __float2bfloat16(f);
    return __builtin_bit_cast(unsigned short, h);
}

// ---------------- weight prep: WT[w][n*256+k] bf16, w = l*5 + t ----------------
// t: 0=Wl[l,0] (writes), 1=Wl[l,1] (rev), 2=Wl[l,2] (cites), 3=Wr[l,0]+Wr[l,2], 4=Wr[l,1]
__global__ void prep_w_k(const float* __restrict__ Wl, const float* __restrict__ Wr,
                         unsigned short* __restrict__ WT) {
    int gid = blockIdx.x * 256 + threadIdx.x;           // 15*65536 threads
    int w = gid >> 16;
    int within = gid & 65535;
    int n = within >> 8, k = within & 255;
    int l = w / 5, t = w % 5;
    float v;
    if (t < 3)       v = Wl[(size_t)((l * 3 + t) * 256 + k) * 256 + n];
    else if (t == 3) v = Wr[(size_t)((l * 3 + 0) * 256 + k) * 256 + n] +
                         Wr[(size_t)((l * 3 + 2) * 256 + k) * 256 + n];
    else             v = Wr[(size_t)((l * 3 + 1) * 256 + k) * 256 + n];
    WT[(size_t)w * 65536 + n * 256 + k] = f2bf(v);
}

__global__ void prep_bias_k(const float* __restrict__ bl,
                            float* __restrict__ biasP, float* __restrict__ biasA) {
    int gid = blockIdx.x * 256 + threadIdx.x;           // 3*256 threads
    int l = gid >> 8, n = gid & 255;
    biasP[l * 256 + n] = bl[(l * 3 + 0) * 256 + n] + bl[(l * 3 + 2) * 256 + n];
    biasA[l * 256 + n] = bl[(l * 3 + 1) * 256 + n];
}

// ---------------- degree count + reciprocal ----------------
__global__ void count_k(const int* __restrict__ dst, int* __restrict__ cnt, int E) {
    int g = blockIdx.x * 256 + threadIdx.x;
    if (g < E) atomicAdd(&cnt[dst[g]], 1);
}
__global__ void inv_k(const int* __restrict__ cnt, float* __restrict__ inv, int n) {
    int g = blockIdx.x * 256 + threadIdx.x;
    if (g < n) inv[g] = 1.0f / (float)max(cnt[g], 1);
}

// ---------------- f32 -> bf16 cast (8 elems/thread) ----------------
__global__ void cast_bf16_k(const float* __restrict__ x, unsigned short* __restrict__ o, int n8) {
    int g = blockIdx.x * 256 + threadIdx.x;
    if (g >= n8) return;
    const float4* xp = reinterpret_cast<const float4*>(x) + (size_t)g * 2;
    float4 a = xp[0], b = xp[1];
    union { unsigned short u[8]; uint4 v; } r;
    r.u[0] = f2bf(a.x); r.u[1] = f2bf(a.y); r.u[2] = f2bf(a.z); r.u[3] = f2bf(a.w);
    r.u[4] = f2bf(b.x); r.u[5] = f2bf(b.y); r.u[6] = f2bf(b.z); r.u[7] = f2bf(b.w);
    reinterpret_cast<uint4*>(o)[g] = r.v;
}

// ---------------- bf16 MFMA GEMM: C[M,256] = A[M,256] @ W  (+bias) ----------------
// WT is [256 n][256 k] (i.e. W transposed), bf16. Grid: (ceil(M/64), 2). Block 256.
template <bool OUT_BF16, bool BIAS>
__global__ __launch_bounds__(256, 2)
void gemm_k(const unsigned short* __restrict__ A, const unsigned short* __restrict__ WT,
            const float* __restrict__ bias, void* __restrict__ Cout, int M) {
    __shared__ uint4 bsh4[4096];                        // 64 KiB: 128 n-rows x 256 k
    char* bsh = reinterpret_cast<char*>(bsh4);
    const int tid = threadIdx.x;
    const int nhalf = blockIdx.y;
    const unsigned short* Wt = WT + nhalf * (128 * 256);

    #pragma unroll
    for (int i = 0; i < 16; ++i) {                      // stage half of B, swizzled
        int c = i * 256 + tid;                          // 4096 chunks of 8 bf16
        int n = c >> 5, kc = c & 31;
        uint4 v = *reinterpret_cast<const uint4*>(Wt + n * 256 + kc * 8);
        int byte = (n * 512 + kc * 16) ^ ((n & 7) << 4);
        *reinterpret_cast<uint4*>(bsh + byte) = v;
    }
    __syncthreads();

    const int wid = tid >> 6;
    const int l = tid & 63;
    const int kgrp = (l >> 4) << 3;                     // 0,8,16,24
    int row = blockIdx.x * 64 + (wid << 4) + (l & 15);
    int rowc = row < M ? row : M - 1;

    uint4 a4[8];
    const unsigned short* Arow = A + (size_t)rowc * 256 + kgrp;
    #pragma unroll
    for (int s = 0; s < 8; ++s)
        a4[s] = *reinterpret_cast<const uint4*>(Arow + s * 32);

    f32x4 acc[8];
    #pragma unroll
    for (int t = 0; t < 8; ++t) acc[t] = f32x4{0.f, 0.f, 0.f, 0.f};

    #pragma unroll
    for (int s = 0; s < 8; ++s) {
        short8 a = __builtin_bit_cast(short8, a4[s]);
        #pragma unroll
        for (int t = 0; t < 8; ++t) {
            int nl = (t << 4) + (l & 15);
            int byte = (nl * 512 + s * 64 + kgrp * 2) ^ ((nl & 7) << 4);
            short8 b = __builtin_bit_cast(short8, *reinterpret_cast<const uint4*>(bsh + byte));
            acc[t] = __builtin_amdgcn_mfma_f32_16x16x32_bf16(a, b, acc[t], 0, 0, 0);
        }
    }

    const int col = l & 15;
    const int rbase = blockIdx.x * 64 + (wid << 4) + ((l >> 4) << 2);
    const int gcol0 = nhalf * 128;
    #pragma unroll
    for (int t = 0; t < 8; ++t) {
        int gc = gcol0 + (t << 4) + col;
        float badd = BIAS ? bias[gc] : 0.f;
        #pragma unroll
        for (int j = 0; j < 4; ++j) {
            int r = rbase + j;
            if (r < M) {
                float v = acc[t][j] + badd;
                if (OUT_BF16)
                    reinterpret_cast<unsigned short*>(Cout)[(size_t)r * 256 + gc] = f2bf(v);
                else
                    reinterpret_cast<float*>(Cout)[(size_t)r * 256 + gc] = v;
            }
        }
    }
}

// ---------------- edge aggregation: out[dst] += y[src] * inv[dst] ----------------
// 32 lanes per edge, 8 f32 each.
__global__ void agg_k(const unsigned short* __restrict__ y, const int* __restrict__ eS,
                      const int* __restrict__ eD, const float* __restrict__ inv,
                      float* __restrict__ out, int E) {
    int t = blockIdx.x * 256 + threadIdx.x;
    int e = t >> 5;
    if (e >= E) return;
    int lane = t & 31;
    int s = eS[e], d = eD[e];
    float sc = inv[d];
    uint4 v = *reinterpret_cast<const uint4*>(y + (size_t)s * 256 + (lane << 3));
    float* op = out + (size_t)d * 256 + (lane << 3);
    atomicAdd(op + 0, bf2f(v.x & 0xffffu) * sc);
    atomicAdd(op + 1, bf2f(v.x >> 16) * sc);
    atomicAdd(op + 2, bf2f(v.y & 0xffffu) * sc);
    atomicAdd(op + 3, bf2f(v.y >> 16) * sc);
    atomicAdd(op + 4, bf2f(v.z & 0xffffu) * sc);
    atomicAdd(op + 5, bf2f(v.z >> 16) * sc);
    atomicAdd(op + 6, bf2f(v.w & 0xffffu) * sc);
    atomicAdd(op + 7, bf2f(v.w >> 16) * sc);
}

extern "C" void kernel_launch(void* const* d_in, const int* in_sizes, int n_in,
                              void* d_out, int out_size, void* d_ws, size_t ws_size,
                              hipStream_t stream) {
    const float* x_author = (const float*)d_in[0];
    const float* x_paper  = (const float*)d_in[1];
    const int* e_w = (const int*)d_in[2];
    const int* e_r = (const int*)d_in[3];
    const int* e_c = (const int*)d_in[4];
    const float* Wl = (const float*)d_in[5];
    const float* bl = (const float*)d_in[6];
    const float* Wr = (const float*)d_in[7];
    const int E = in_sizes[2] / 2;

    float* outA = (float*)d_out;                 // [NA,256]
    float* outP = (float*)d_out + (size_t)NA * HH; // [NP,256]

    // workspace carve
    size_t off = 0;
    auto carve = [&](size_t bytes) {
        void* p = (char*)d_ws + off;
        off += (bytes + 255) & ~(size_t)255;
        return p;
    };
    unsigned short* xp_bf = (unsigned short*)carve((size_t)NP * HH * 2);
    unsigned short* xa_bf = (unsigned short*)carve((size_t)NA * HH * 2);
    unsigned short* ybuf  = (unsigned short*)carve((size_t)NP * HH * 2);
    unsigned short* WT    = (unsigned short*)carve((size_t)15 * 65536 * 2);
    float* biasP = (float*)carve((size_t)LL * HH * 4);
    float* biasA = (float*)carve((size_t)LL * HH * 4);
    int*   cnt   = (int*)carve((size_t)(2 * NP + NA) * 4);   // [w:NP][c:NP][r:NA]
    float* invv  = (float*)carve((size_t)(2 * NP + NA) * 4);
    (void)off; (void)ws_size; (void)n_in; (void)out_size;

    int* cnt_w = cnt;          int* cnt_c = cnt + NP;        int* cnt_r = cnt + 2 * NP;
    float* inv_w = invv;       float* inv_c = invv + NP;     float* inv_r = invv + 2 * NP;

    // one-time per call: weights, biases, degree counts
    hipMemsetAsync(cnt, 0, (size_t)(2 * NP + NA) * 4, stream);
    prep_w_k<<<3840, 256, 0, stream>>>(Wl, Wr, WT);
    prep_bias_k<<<3, 256, 0, stream>>>(bl, biasP, biasA);
    int egrid = (E + 255) / 256;
    count_k<<<egrid, 256, 0, stream>>>(e_w + E, cnt_w, E);
    count_k<<<egrid, 256, 0, stream>>>(e_c + E, cnt_c, E);
    count_k<<<egrid, 256, 0, stream>>>(e_r + E, cnt_r, E);
    inv_k<<<(2 * NP + NA + 255) / 256, 256, 0, stream>>>(cnt, invv, 2 * NP + NA);

    const int mtA = (NA + 63) / 64, mtP = (NP + 63) / 64;
    const int aggGrid = (E * 32 + 255) / 256;

    for (int l = 0; l < LL; ++l) {
        const float* srcA = (l == 0) ? x_author : outA;
        const float* srcP = (l == 0) ? x_paper : outP;
        cast_bf16_k<<<(NP * HH / 8 + 255) / 256, 256, 0, stream>>>(srcP, xp_bf, NP * HH / 8);
        cast_bf16_k<<<(NA * HH / 8 + 255) / 256, 256, 0, stream>>>(srcA, xa_bf, NA * HH / 8);

        const unsigned short* WT_l = WT + (size_t)l * 5 * 65536;
        // root terms (overwrite out buffers, f32, +bias)
        gemm_k<false, true><<<dim3(mtP, 2), 256, 0, stream>>>(xp_bf, WT_l + 3 * 65536, biasP + l * 256, outP, NP);
        gemm_k<false, true><<<dim3(mtA, 2), 256, 0, stream>>>(xa_bf, WT_l + 4 * 65536, biasA + l * 256, outA, NA);
        // writes: authors -> papers
        gemm_k<true, false><<<dim3(mtA, 2), 256, 0, stream>>>(xa_bf, WT_l + 0 * 65536, nullptr, ybuf, NA);
        agg_k<<<aggGrid, 256, 0, stream>>>(ybuf, e_w, e_w + E, inv_w, outP, E);
        // cites: papers -> papers
        gemm_k<true, false><<<dim3(mtP, 2), 256, 0, stream>>>(xp_bf, WT_l + 2 * 65536, nullptr, ybuf, NP);
        agg_k<<<aggGrid, 256, 0, stream>>>(ybuf, e_c, e_c + E, inv_c, outP, E);
        // rev: papers -> authors
        gemm_k<true, false><<<dim3(mtP, 2), 256, 0, stream>>>(xp_bf, WT_l + 1 * 65536, nullptr, ybuf, NP);
        agg_k<<<aggGrid, 256, 0, stream>>>(ybuf, e_r, e_r + E, inv_r, outA, E);
    }
}

// Round 3
// 1248.256 us; speedup vs baseline: 25.3797x; 25.3797x over previous
//
#include <hip/hip_runtime.h>
#include <hip/hip_bf16.h>
#include <cstdint>
#include <cstddef>

#define NA 50000
#define NP 100000
#define HH 256
#define LL 3

typedef __attribute__((ext_vector_type(8))) short short8;
typedef __attribute__((ext_vector_type(4))) float f32x4;

__device__ __forceinline__ float bf2f(unsigned int u16) {
    unsigned int x = u16 << 16;
    return __builtin_bit_cast(float, x);
}
__device__ __forceinline__ unsigned short f2bf(float f) {
    __hip_bfloat16 h = __float2bfloat16(f);
    return __builtin_bit_cast(unsigned short, h);
}

// ---------------- weight prep: WT[w][n*256+k] bf16, w = l*5 + t ----------------
// t0=Wl[l,0] (writes), t1=Wl[l,2] (cites), t2=Wr[l,0]+Wr[l,2] (P-root),
// t3=Wl[l,1] (rev), t4=Wr[l,1] (A-root)
__global__ void prep_w_k(const float* __restrict__ Wl, const float* __restrict__ Wr,
                         unsigned short* __restrict__ WT) {
    int gid = blockIdx.x * 256 + threadIdx.x;           // 15*65536 threads
    int w = gid >> 16;
    int within = gid & 65535;
    int n = within >> 8, k = within & 255;
    int l = w / 5, t = w % 5;
    float v;
    if (t == 0)      v = Wl[(size_t)((l * 3 + 0) * 256 + k) * 256 + n];
    else if (t == 1) v = Wl[(size_t)((l * 3 + 2) * 256 + k) * 256 + n];
    else if (t == 2) v = Wr[(size_t)((l * 3 + 0) * 256 + k) * 256 + n] +
                         Wr[(size_t)((l * 3 + 2) * 256 + k) * 256 + n];
    else if (t == 3) v = Wl[(size_t)((l * 3 + 1) * 256 + k) * 256 + n];
    else             v = Wr[(size_t)((l * 3 + 1) * 256 + k) * 256 + n];
    WT[(size_t)w * 65536 + n * 256 + k] = f2bf(v);
}

__global__ void prep_bias_k(const float* __restrict__ bl,
                            float* __restrict__ biasP, float* __restrict__ biasA) {
    int gid = blockIdx.x * 256 + threadIdx.x;           // 3*256 threads
    int l = gid >> 8, n = gid & 255;
    biasP[l * 256 + n] = bl[(l * 3 + 0) * 256 + n] + bl[(l * 3 + 2) * 256 + n];
    biasA[l * 256 + n] = bl[(l * 3 + 1) * 256 + n];
}

// ---------------- degree / CSR build ----------------
__global__ void count_k(const int* __restrict__ dst, int* __restrict__ cnt, int E) {
    int g = blockIdx.x * 256 + threadIdx.x;
    if (g < E) atomicAdd(&cnt[dst[g]], 1);
}
__global__ void inv_k(const int* __restrict__ cnt, float* __restrict__ inv, int n) {
    int g = blockIdx.x * 256 + threadIdx.x;
    if (g < n) inv[g] = 1.0f / (float)max(cnt[g], 1);
}

__global__ void scanA_k(const int* __restrict__ cnt, int* __restrict__ part, int n) {
    __shared__ int sh[256];
    int i = blockIdx.x * 256 + threadIdx.x;
    sh[threadIdx.x] = (i < n) ? cnt[i] : 0;
    __syncthreads();
    for (int s = 128; s > 0; s >>= 1) {
        if (threadIdx.x < s) sh[threadIdx.x] += sh[threadIdx.x + s];
        __syncthreads();
    }
    if (threadIdx.x == 0) part[blockIdx.x] = sh[0];
}
__global__ void scanB_k(int* part, int nb) {
    if (threadIdx.x == 0 && blockIdx.x == 0) {
        int run = 0;
        for (int i = 0; i < nb; ++i) { int v = part[i]; part[i] = run; run += v; }
    }
}
__global__ void scanC_k(const int* __restrict__ cnt, const int* __restrict__ part,
                        int* __restrict__ rowptr, int n) {
    __shared__ int sh[256];
    int t = threadIdx.x;
    int i = blockIdx.x * 256 + t;
    int v = (i < n) ? cnt[i] : 0;
    sh[t] = v;
    __syncthreads();
    for (int off = 1; off < 256; off <<= 1) {
        int x = (t >= off) ? sh[t - off] : 0;
        __syncthreads();
        if (t >= off) sh[t] += x;
        __syncthreads();
    }
    if (i < n) {
        int incl = sh[t];
        rowptr[i] = part[blockIdx.x] + incl - v;
        if (i == n - 1) rowptr[n] = part[blockIdx.x] + incl;
    }
}
__global__ void fill_k(const int* __restrict__ src, const int* __restrict__ dst,
                       const int* __restrict__ rowptr, int* __restrict__ cursor,
                       int* __restrict__ col, int E) {
    int e = blockIdx.x * 256 + threadIdx.x;
    if (e >= E) return;
    int d = dst[e];
    int pos = atomicAdd(&cursor[d], 1);
    col[rowptr[d] + pos] = src[e];
}

// ---------------- f32 -> bf16 cast (8 elems/thread) ----------------
__global__ void cast_bf16_k(const float* __restrict__ x, unsigned short* __restrict__ o, int n8) {
    int g = blockIdx.x * 256 + threadIdx.x;
    if (g >= n8) return;
    const float4* xp = reinterpret_cast<const float4*>(x) + (size_t)g * 2;
    float4 a = xp[0], b = xp[1];
    union { unsigned short u[8]; uint4 v; } r;
    r.u[0] = f2bf(a.x); r.u[1] = f2bf(a.y); r.u[2] = f2bf(a.z); r.u[3] = f2bf(a.w);
    r.u[4] = f2bf(b.x); r.u[5] = f2bf(b.y); r.u[6] = f2bf(b.z); r.u[7] = f2bf(b.w);
    reinterpret_cast<uint4*>(o)[g] = r.v;
}

// ---------------- CSR gather-mean: mean[d] = (1/deg) * sum_{j in N(d)} x[j] ----------------
__global__ void agg_mean_k(const unsigned short* __restrict__ x,
                           const int* __restrict__ rowptr, const int* __restrict__ col,
                           unsigned short* __restrict__ mean, int n_dst) {
    int node = blockIdx.x * 4 + (threadIdx.x >> 6);
    if (node >= n_dst) return;
    int lane = threadIdx.x & 63;
    int beg = rowptr[node], end = rowptr[node + 1];
    float a0 = 0.f, a1 = 0.f, a2 = 0.f, a3 = 0.f;
    int j = beg;
    for (; j + 1 < end; j += 2) {
        int s0 = col[j], s1 = col[j + 1];
        uint2 v0 = *reinterpret_cast<const uint2*>(x + (size_t)s0 * 256 + lane * 4);
        uint2 v1 = *reinterpret_cast<const uint2*>(x + (size_t)s1 * 256 + lane * 4);
        a0 += bf2f(v0.x & 0xffffu); a1 += bf2f(v0.x >> 16);
        a2 += bf2f(v0.y & 0xffffu); a3 += bf2f(v0.y >> 16);
        a0 += bf2f(v1.x & 0xffffu); a1 += bf2f(v1.x >> 16);
        a2 += bf2f(v1.y & 0xffffu); a3 += bf2f(v1.y >> 16);
    }
    if (j < end) {
        int s0 = col[j];
        uint2 v0 = *reinterpret_cast<const uint2*>(x + (size_t)s0 * 256 + lane * 4);
        a0 += bf2f(v0.x & 0xffffu); a1 += bf2f(v0.x >> 16);
        a2 += bf2f(v0.y & 0xffffu); a3 += bf2f(v0.y >> 16);
    }
    float sc = (end > beg) ? 1.0f / (float)(end - beg) : 0.f;
    uint2 r;
    r.x = (unsigned int)f2bf(a0 * sc) | ((unsigned int)f2bf(a1 * sc) << 16);
    r.y = (unsigned int)f2bf(a2 * sc) | ((unsigned int)f2bf(a3 * sc) << 16);
    *reinterpret_cast<uint2*>(mean + (size_t)node * 256 + lane * 4) = r;
}

// ---------------- atomic scatter-add fallback: out[dst] += y[src] * inv[dst] ----------------
__global__ void agg_atomic_k(const unsigned short* __restrict__ y, const int* __restrict__ eS,
                             const int* __restrict__ eD, const float* __restrict__ inv,
                             float* __restrict__ out, int E) {
    int t = blockIdx.x * 256 + threadIdx.x;
    int e = t >> 5;
    if (e >= E) return;
    int lane = t & 31;
    int s = eS[e], d = eD[e];
    float sc = inv[d];
    uint4 v = *reinterpret_cast<const uint4*>(y + (size_t)s * 256 + (lane << 3));
    float* op = out + (size_t)d * 256 + (lane << 3);
    atomicAdd(op + 0, bf2f(v.x & 0xffffu) * sc);
    atomicAdd(op + 1, bf2f(v.x >> 16) * sc);
    atomicAdd(op + 2, bf2f(v.y & 0xffffu) * sc);
    atomicAdd(op + 3, bf2f(v.y >> 16) * sc);
    atomicAdd(op + 4, bf2f(v.z & 0xffffu) * sc);
    atomicAdd(op + 5, bf2f(v.z >> 16) * sc);
    atomicAdd(op + 6, bf2f(v.w & 0xffffu) * sc);
    atomicAdd(op + 7, bf2f(v.w >> 16) * sc);
}

// ---------------- multi-part bf16 MFMA GEMM: C[M,256] = sum_p A_p[M,256] @ W_p (+bias) ----
template <int PARTS, bool OUT_BF16, bool BIAS>
__global__ __launch_bounds__(256, 2)
void gemmN_k(const unsigned short* __restrict__ A0,
             const unsigned short* __restrict__ A1,
             const unsigned short* __restrict__ A2,
             const unsigned short* __restrict__ WT,
             const float* __restrict__ bias, void* __restrict__ Cout, int M) {
    __shared__ uint4 bsh4[4096];                        // 64 KiB: 128 n-rows x 256 k, swizzled
    char* bsh = reinterpret_cast<char*>(bsh4);
    const int tid = threadIdx.x;
    const int nhalf = blockIdx.y;

    const int wid = tid >> 6;
    const int l = tid & 63;
    const int kgrp = (l >> 4) << 3;                     // 0,8,16,24
    int row = blockIdx.x * 64 + (wid << 4) + (l & 15);
    int rowc = row < M ? row : M - 1;

    f32x4 acc[8];
    #pragma unroll
    for (int t = 0; t < 8; ++t) acc[t] = f32x4{0.f, 0.f, 0.f, 0.f};

    #pragma unroll
    for (int p = 0; p < PARTS; ++p) {
        if (p) __syncthreads();
        const unsigned short* Wt = WT + (size_t)p * 65536 + nhalf * (128 * 256);
        #pragma unroll
        for (int i = 0; i < 16; ++i) {                  // stage 128x256 bf16, swizzled
            int c = i * 256 + tid;
            int n = c >> 5, kc = c & 31;
            uint4 v = *reinterpret_cast<const uint4*>(Wt + n * 256 + kc * 8);
            int byte = (n * 512 + kc * 16) ^ ((n & 7) << 4);
            *reinterpret_cast<uint4*>(bsh + byte) = v;
        }
        __syncthreads();

        const unsigned short* Ap = (p == 0) ? A0 : (p == 1) ? A1 : A2;
        const unsigned short* Arow = Ap + (size_t)rowc * 256 + kgrp;
        uint4 a4[8];
        #pragma unroll
        for (int s = 0; s < 8; ++s)
            a4[s] = *reinterpret_cast<const uint4*>(Arow + s * 32);

        #pragma unroll
        for (int s = 0; s < 8; ++s) {
            short8 a = __builtin_bit_cast(short8, a4[s]);
            #pragma unroll
            for (int t = 0; t < 8; ++t) {
                int nl = (t << 4) + (l & 15);
                int byte = (nl * 512 + s * 64 + kgrp * 2) ^ ((nl & 7) << 4);
                short8 b = __builtin_bit_cast(short8, *reinterpret_cast<const uint4*>(bsh + byte));
                acc[t] = __builtin_amdgcn_mfma_f32_16x16x32_bf16(a, b, acc[t], 0, 0, 0);
            }
        }
    }

    const int col = l & 15;
    const int rbase = blockIdx.x * 64 + (wid << 4) + ((l >> 4) << 2);
    const int gcol0 = nhalf * 128;
    #pragma unroll
    for (int t = 0; t < 8; ++t) {
        int gc = gcol0 + (t << 4) + col;
        float badd = BIAS ? bias[gc] : 0.f;
        #pragma unroll
        for (int j = 0; j < 4; ++j) {
            int r = rbase + j;
            if (r < M) {
                float v = acc[t][j] + badd;
                if (OUT_BF16)
                    reinterpret_cast<unsigned short*>(Cout)[(size_t)r * 256 + gc] = f2bf(v);
                else
                    reinterpret_cast<float*>(Cout)[(size_t)r * 256 + gc] = v;
            }
        }
    }
}

extern "C" void kernel_launch(void* const* d_in, const int* in_sizes, int n_in,
                              void* d_out, int out_size, void* d_ws, size_t ws_size,
                              hipStream_t stream) {
    const float* x_author = (const float*)d_in[0];
    const float* x_paper  = (const float*)d_in[1];
    const int* e_w = (const int*)d_in[2];
    const int* e_r = (const int*)d_in[3];
    const int* e_c = (const int*)d_in[4];
    const float* Wl = (const float*)d_in[5];
    const float* bl = (const float*)d_in[6];
    const float* Wr = (const float*)d_in[7];
    const int E = in_sizes[2] / 2;

    float* outA = (float*)d_out;                         // [NA,256] f32
    float* outP = (float*)d_out + (size_t)NA * HH;       // [NP,256] f32

    const int egrid = (E + 255) / 256;
    const int nbP = (NP + 255) / 256, nbA = (NA + 255) / 256;
    const int mtA = (NA + 63) / 64, mtP = (NP + 63) / 64;

    // ================= Layout A (aggregate-first CSR, ~215 MB) =================
    size_t offA = 0;
    auto carveA = [&](size_t bytes) {
        void* p = (char*)d_ws + offA;
        offA += (bytes + 255) & ~(size_t)255;
        return p;
    };
    unsigned short* xa0   = (unsigned short*)carveA((size_t)NA * HH * 2);
    unsigned short* xp0   = (unsigned short*)carveA((size_t)NP * HH * 2);
    unsigned short* meanW = (unsigned short*)carveA((size_t)NP * HH * 2);
    unsigned short* meanC = (unsigned short*)carveA((size_t)NP * HH * 2);
    unsigned short* meanR = (unsigned short*)carveA((size_t)NA * HH * 2);
    unsigned short* WT_A  = (unsigned short*)carveA((size_t)15 * 65536 * 2);
    float* biasP_A = (float*)carveA((size_t)LL * HH * 4);
    float* biasA_A = (float*)carveA((size_t)LL * HH * 4);
    int* cntA   = (int*)carveA((size_t)(2 * NP + NA) * 4);   // reused as fill cursor
    int* rp_w   = (int*)carveA((size_t)(NP + 1) * 4);
    int* rp_c   = (int*)carveA((size_t)(NP + 1) * 4);
    int* rp_r   = (int*)carveA((size_t)(NA + 1) * 4);
    int* part   = (int*)carveA((size_t)512 * 4);
    int* col_w  = (int*)carveA((size_t)E * 4);
    int* col_c  = (int*)carveA((size_t)E * 4);
    int* col_r  = (int*)carveA((size_t)E * 4);
    const size_t needA = offA;

    if (needA <= ws_size) {
        // ---- fast path ----
        int* cnt_w = cntA;  int* cnt_c = cntA + NP;  int* cnt_r = cntA + 2 * NP;
        const size_t cntBytes = (size_t)(2 * NP + NA) * 4;

        hipMemsetAsync(cntA, 0, cntBytes, stream);
        prep_w_k<<<3840, 256, 0, stream>>>(Wl, Wr, WT_A);
        prep_bias_k<<<3, 256, 0, stream>>>(bl, biasP_A, biasA_A);
        count_k<<<egrid, 256, 0, stream>>>(e_w + E, cnt_w, E);
        count_k<<<egrid, 256, 0, stream>>>(e_c + E, cnt_c, E);
        count_k<<<egrid, 256, 0, stream>>>(e_r + E, cnt_r, E);
        scanA_k<<<nbP, 256, 0, stream>>>(cnt_w, part, NP);
        scanB_k<<<1, 64, 0, stream>>>(part, nbP);
        scanC_k<<<nbP, 256, 0, stream>>>(cnt_w, part, rp_w, NP);
        scanA_k<<<nbP, 256, 0, stream>>>(cnt_c, part, NP);
        scanB_k<<<1, 64, 0, stream>>>(part, nbP);
        scanC_k<<<nbP, 256, 0, stream>>>(cnt_c, part, rp_c, NP);
        scanA_k<<<nbA, 256, 0, stream>>>(cnt_r, part, NA);
        scanB_k<<<1, 64, 0, stream>>>(part, nbA);
        scanC_k<<<nbA, 256, 0, stream>>>(cnt_r, part, rp_r, NA);
        // reuse cnt as the fill cursor: re-zero it fully (fixes R2's OOB bug)
        hipMemsetAsync(cntA, 0, cntBytes, stream);
        fill_k<<<egrid, 256, 0, stream>>>(e_w, e_w + E, rp_w, cnt_w, col_w, E);
        fill_k<<<egrid, 256, 0, stream>>>(e_c, e_c + E, rp_c, cnt_c, col_c, E);
        fill_k<<<egrid, 256, 0, stream>>>(e_r, e_r + E, rp_r, cnt_r, col_r, E);

        cast_bf16_k<<<(NA * HH / 8 + 255) / 256, 256, 0, stream>>>(x_author, xa0, NA * HH / 8);
        cast_bf16_k<<<(NP * HH / 8 + 255) / 256, 256, 0, stream>>>(x_paper, xp0, NP * HH / 8);

        // bf16 ping set inside d_out (overwritten by f32 at l=2)
        unsigned short* xa1 = (unsigned short*)d_out;
        unsigned short* xp1 = xa1 + (size_t)NA * HH;

        const int agP = (NP + 3) / 4, agA = (NA + 3) / 4;
        unsigned short* xa_cur = xa0; unsigned short* xp_cur = xp0;
        unsigned short* xa_nxt = xa1; unsigned short* xp_nxt = xp1;

        for (int l = 0; l < LL; ++l) {
            const unsigned short* WT_l = WT_A + (size_t)l * 5 * 65536;
            agg_mean_k<<<agP, 256, 0, stream>>>(xa_cur, rp_w, col_w, meanW, NP);
            agg_mean_k<<<agP, 256, 0, stream>>>(xp_cur, rp_c, col_c, meanC, NP);
            agg_mean_k<<<agA, 256, 0, stream>>>(xp_cur, rp_r, col_r, meanR, NA);
            // P parts: meanW@t0 + meanC@t1 + xp@t2 ; A parts: meanR@t3 + xa@t4
            if (l < LL - 1) {
                gemmN_k<3, true, true><<<dim3(mtP, 2), 256, 0, stream>>>(meanW, meanC, xp_cur, WT_l, biasP_A + l * 256, xp_nxt, NP);
                gemmN_k<2, true, true><<<dim3(mtA, 2), 256, 0, stream>>>(meanR, xa_cur, nullptr, WT_l + 3 * 65536, biasA_A + l * 256, xa_nxt, NA);
                unsigned short* t;
                t = xa_cur; xa_cur = xa_nxt; xa_nxt = t;
                t = xp_cur; xp_cur = xp_nxt; xp_nxt = t;
            } else {
                gemmN_k<3, false, true><<<dim3(mtP, 2), 256, 0, stream>>>(meanW, meanC, xp_cur, WT_l, biasP_A + l * 256, outP, NP);
                gemmN_k<2, false, true><<<dim3(mtA, 2), 256, 0, stream>>>(meanR, xa_cur, nullptr, WT_l + 3 * 65536, biasA_A + l * 256, outA, NA);
            }
        }
        return;
    }

    // ================= Layout B (R1-proven fallback, ~132 MB) =================
    size_t offB = 0;
    auto carveB = [&](size_t bytes) {
        void* p = (char*)d_ws + offB;
        offB += (bytes + 255) & ~(size_t)255;
        return p;
    };
    unsigned short* xp_bf = (unsigned short*)carveB((size_t)NP * HH * 2);
    unsigned short* xa_bf = (unsigned short*)carveB((size_t)NA * HH * 2);
    unsigned short* ybuf  = (unsigned short*)carveB((size_t)NP * HH * 2);
    unsigned short* WT_B  = (unsigned short*)carveB((size_t)15 * 65536 * 2);
    float* biasP_B = (float*)carveB((size_t)LL * HH * 4);
    float* biasA_B = (float*)carveB((size_t)LL * HH * 4);
    int*   cntB    = (int*)carveB((size_t)(2 * NP + NA) * 4);
    float* invv    = (float*)carveB((size_t)(2 * NP + NA) * 4);

    int* cnt_w = cntB;       int* cnt_c = cntB + NP;     int* cnt_r = cntB + 2 * NP;
    float* inv_w = invv;     float* inv_c = invv + NP;   float* inv_r = invv + 2 * NP;

    hipMemsetAsync(cntB, 0, (size_t)(2 * NP + NA) * 4, stream);
    prep_w_k<<<3840, 256, 0, stream>>>(Wl, Wr, WT_B);
    prep_bias_k<<<3, 256, 0, stream>>>(bl, biasP_B, biasA_B);
    count_k<<<egrid, 256, 0, stream>>>(e_w + E, cnt_w, E);
    count_k<<<egrid, 256, 0, stream>>>(e_c + E, cnt_c, E);
    count_k<<<egrid, 256, 0, stream>>>(e_r + E, cnt_r, E);
    inv_k<<<(2 * NP + NA + 255) / 256, 256, 0, stream>>>(cntB, invv, 2 * NP + NA);

    const int aggGrid = (E * 32 + 255) / 256;
    for (int l = 0; l < LL; ++l) {
        const float* srcA = (l == 0) ? x_author : outA;
        const float* srcP = (l == 0) ? x_paper : outP;
        cast_bf16_k<<<(NP * HH / 8 + 255) / 256, 256, 0, stream>>>(srcP, xp_bf, NP * HH / 8);
        cast_bf16_k<<<(NA * HH / 8 + 255) / 256, 256, 0, stream>>>(srcA, xa_bf, NA * HH / 8);

        const unsigned short* WT_l = WT_B + (size_t)l * 5 * 65536;
        // roots (overwrite f32 out, +bias): P-root = t2, A-root = t4
        gemmN_k<1, false, true><<<dim3(mtP, 2), 256, 0, stream>>>(xp_bf, nullptr, nullptr, WT_l + 2 * 65536, biasP_B + l * 256, outP, NP);
        gemmN_k<1, false, true><<<dim3(mtA, 2), 256, 0, stream>>>(xa_bf, nullptr, nullptr, WT_l + 4 * 65536, biasA_B + l * 256, outA, NA);
        // writes (t0): authors -> papers
        gemmN_k<1, true, false><<<dim3(mtA, 2), 256, 0, stream>>>(xa_bf, nullptr, nullptr, WT_l + 0 * 65536, nullptr, ybuf, NA);
        agg_atomic_k<<<aggGrid, 256, 0, stream>>>(ybuf, e_w, e_w + E, inv_w, outP, E);
        // cites (t1): papers -> papers
        gemmN_k<1, true, false><<<dim3(mtP, 2), 256, 0, stream>>>(xp_bf, nullptr, nullptr, WT_l + 1 * 65536, nullptr, ybuf, NP);
        agg_atomic_k<<<aggGrid, 256, 0, stream>>>(ybuf, e_c, e_c + E, inv_c, outP, E);
        // rev (t3): papers -> authors
        gemmN_k<1, true, false><<<dim3(mtP, 2), 256, 0, stream>>>(xp_bf, nullptr, nullptr, WT_l + 3 * 65536, nullptr, ybuf, NP);
        agg_atomic_k<<<aggGrid, 256, 0, stream>>>(ybuf, e_r, e_r + E, inv_r, outA, E);
    }
    (void)n_in; (void)out_size; (void)ws_size;
}

// Round 4
// 1167.522 us; speedup vs baseline: 27.1347x; 1.0691x over previous
//
#include <hip/hip_runtime.h>
#include <hip/hip_bf16.h>
#include <cstdint>
#include <cstddef>

#define NA 50000
#define NP 100000
#define HH 256
#define LL 3
#define GP 25000            // NP/4 agg blocks
#define GA 12500            // NA/4 agg blocks

typedef __attribute__((ext_vector_type(8))) short short8;
typedef __attribute__((ext_vector_type(4))) float f32x4;

__device__ __forceinline__ float bf2f(unsigned int u16) {
    unsigned int x = u16 << 16;
    return __builtin_bit_cast(float, x);
}
__device__ __forceinline__ unsigned short f2bf(float f) {
    __hip_bfloat16 h = __float2bfloat16(f);
    return __builtin_bit_cast(unsigned short, h);
}

// ---------------- weight prep: WT[w][n*256+k] bf16, w = l*5 + t ----------------
// t0=Wl[l,0] (writes), t1=Wl[l,2] (cites), t2=Wr[l,0]+Wr[l,2] (P-root),
// t3=Wl[l,1] (rev), t4=Wr[l,1] (A-root)
__global__ void prep_w_k(const float* __restrict__ Wl, const float* __restrict__ Wr,
                         unsigned short* __restrict__ WT) {
    int gid = blockIdx.x * 256 + threadIdx.x;           // 15*65536 threads
    int w = gid >> 16;
    int within = gid & 65535;
    int n = within >> 8, k = within & 255;
    int l = w / 5, t = w % 5;
    float v;
    if (t == 0)      v = Wl[(size_t)((l * 3 + 0) * 256 + k) * 256 + n];
    else if (t == 1) v = Wl[(size_t)((l * 3 + 2) * 256 + k) * 256 + n];
    else if (t == 2) v = Wr[(size_t)((l * 3 + 0) * 256 + k) * 256 + n] +
                         Wr[(size_t)((l * 3 + 2) * 256 + k) * 256 + n];
    else if (t == 3) v = Wl[(size_t)((l * 3 + 1) * 256 + k) * 256 + n];
    else             v = Wr[(size_t)((l * 3 + 1) * 256 + k) * 256 + n];
    WT[(size_t)w * 65536 + n * 256 + k] = f2bf(v);
}

__global__ void prep_bias_k(const float* __restrict__ bl,
                            float* __restrict__ biasP, float* __restrict__ biasA) {
    int gid = blockIdx.x * 256 + threadIdx.x;           // 3*256 threads
    int l = gid >> 8, n = gid & 255;
    biasP[l * 256 + n] = bl[(l * 3 + 0) * 256 + n] + bl[(l * 3 + 2) * 256 + n];
    biasA[l * 256 + n] = bl[(l * 3 + 1) * 256 + n];
}

// ---------------- CSR build (fused over the 3 edge types) ----------------
// cnt layout: [w: NP][c: NP][r: NA]
__global__ void count3_k(const int* __restrict__ dw, const int* __restrict__ dc,
                         const int* __restrict__ dr, int* __restrict__ cnt,
                         int E, int egrid) {
    int b = blockIdx.x;
    int type = b / egrid, lb = b - type * egrid;
    int e = lb * 256 + threadIdx.x;
    if (e >= E) return;
    const int* d = (type == 0) ? dw : (type == 1) ? dc : dr;
    int base = (type == 0) ? 0 : (type == 1) ? NP : 2 * NP;
    atomicAdd(&cnt[base + d[e]], 1);
}

// per-256-block sums into part[type*512 + localblock]
__global__ void scanA_k(const int* __restrict__ cnt, int* __restrict__ part,
                        int nbP, int nbA) {
    int b = blockIdx.x;
    int type, lb;
    if (b < nbP) { type = 0; lb = b; }
    else if (b < 2 * nbP) { type = 1; lb = b - nbP; }
    else { type = 2; lb = b - 2 * nbP; }
    int n = (type < 2) ? NP : NA;
    int base = (type == 0) ? 0 : (type == 1) ? NP : 2 * NP;
    __shared__ int sh[256];
    int i = lb * 256 + threadIdx.x;
    sh[threadIdx.x] = (i < n) ? cnt[base + i] : 0;
    __syncthreads();
    for (int s = 128; s > 0; s >>= 1) {
        if (threadIdx.x < s) sh[threadIdx.x] += sh[threadIdx.x + s];
        __syncthreads();
    }
    if (threadIdx.x == 0) part[type * 512 + lb] = sh[0];
}
// exclusive-scan each type's part segment with one 512-thread block
__global__ void scanB_k(int* __restrict__ part, int nbP, int nbA) {
    int type = blockIdx.x;
    int nb = (type < 2) ? nbP : nbA;
    int* seg = part + type * 512;
    __shared__ int sh[512];
    int t = threadIdx.x;
    int v0 = (t < nb) ? seg[t] : 0;
    sh[t] = v0;
    __syncthreads();
    for (int off = 1; off < 512; off <<= 1) {
        int x = (t >= off) ? sh[t - off] : 0;
        __syncthreads();
        sh[t] += x;
        __syncthreads();
    }
    if (t < nb) seg[t] = sh[t] - v0;                    // exclusive
}
__global__ void scanC_k(const int* __restrict__ cnt, const int* __restrict__ part,
                        int* __restrict__ rp_w, int* __restrict__ rp_c,
                        int* __restrict__ rp_r, int nbP, int nbA) {
    int b = blockIdx.x;
    int type, lb;
    if (b < nbP) { type = 0; lb = b; }
    else if (b < 2 * nbP) { type = 1; lb = b - nbP; }
    else { type = 2; lb = b - 2 * nbP; }
    int n = (type < 2) ? NP : NA;
    int base = (type == 0) ? 0 : (type == 1) ? NP : 2 * NP;
    int* rowptr = (type == 0) ? rp_w : (type == 1) ? rp_c : rp_r;
    __shared__ int sh[256];
    int t = threadIdx.x;
    int i = lb * 256 + t;
    int v = (i < n) ? cnt[base + i] : 0;
    sh[t] = v;
    __syncthreads();
    for (int off = 1; off < 256; off <<= 1) {
        int x = (t >= off) ? sh[t - off] : 0;
        __syncthreads();
        if (t >= off) sh[t] += x;
        __syncthreads();
    }
    if (i < n) {
        int incl = sh[t];
        int pb = part[type * 512 + lb];
        rowptr[i] = pb + incl - v;
        if (i == n - 1) rowptr[n] = pb + incl;
    }
}
__global__ void fill3_k(const int* __restrict__ e_w, const int* __restrict__ e_c,
                        const int* __restrict__ e_r,
                        const int* __restrict__ rp_w, const int* __restrict__ rp_c,
                        const int* __restrict__ rp_r,
                        int* __restrict__ cursor,
                        int* __restrict__ col_w, int* __restrict__ col_c,
                        int* __restrict__ col_r, int E, int egrid) {
    int b = blockIdx.x;
    int type = b / egrid, lb = b - type * egrid;
    int e = lb * 256 + threadIdx.x;
    if (e >= E) return;
    const int* ep = (type == 0) ? e_w : (type == 1) ? e_c : e_r;
    const int* rowptr = (type == 0) ? rp_w : (type == 1) ? rp_c : rp_r;
    int* col = (type == 0) ? col_w : (type == 1) ? col_c : col_r;
    int base = (type == 0) ? 0 : (type == 1) ? NP : 2 * NP;
    int s = ep[e], d = ep[E + e];
    int pos = atomicAdd(&cursor[base + d], 1);
    col[rowptr[d] + pos] = s;
}

// ---------------- f32 -> bf16 cast (8 elems/thread) ----------------
__global__ void cast_bf16_k(const float* __restrict__ x, unsigned short* __restrict__ o, int n8) {
    int g = blockIdx.x * 256 + threadIdx.x;
    if (g >= n8) return;
    const float4* xp = reinterpret_cast<const float4*>(x) + (size_t)g * 2;
    float4 a = xp[0], b = xp[1];
    union { unsigned short u[8]; uint4 v; } r;
    r.u[0] = f2bf(a.x); r.u[1] = f2bf(a.y); r.u[2] = f2bf(a.z); r.u[3] = f2bf(a.w);
    r.u[4] = f2bf(b.x); r.u[5] = f2bf(b.y); r.u[6] = f2bf(b.z); r.u[7] = f2bf(b.w);
    reinterpret_cast<uint4*>(o)[g] = r.v;
}

// ---------------- fused CSR gather-mean: 3 jobs in one dispatch ----------------
// wave per node; two 32-lane halves take alternate edges; uint4 (16B) per lane
// covers the full 512B row; halves combined with shfl_xor(32).
__global__ void agg_fused_k(const unsigned short* __restrict__ xa,
                            const unsigned short* __restrict__ xp,
                            const int* __restrict__ rp_w, const int* __restrict__ col_w,
                            const int* __restrict__ rp_c, const int* __restrict__ col_c,
                            const int* __restrict__ rp_r, const int* __restrict__ col_r,
                            unsigned short* __restrict__ mW,
                            unsigned short* __restrict__ mC,
                            unsigned short* __restrict__ mR) {
    int b = blockIdx.x;
    const unsigned short* x; const int* rp; const int* cl; unsigned short* mn; int nd;
    if (b < GP)            { x = xa; rp = rp_w; cl = col_w; mn = mW; nd = NP; }
    else if (b < 2 * GP)   { b -= GP; x = xp; rp = rp_c; cl = col_c; mn = mC; nd = NP; }
    else                   { b -= 2 * GP; x = xp; rp = rp_r; cl = col_r; mn = mR; nd = NA; }
    int node = b * 4 + (threadIdx.x >> 6);
    if (node >= nd) return;
    int lane = threadIdx.x & 63;
    int half = lane >> 5, l32 = lane & 31;
    int beg = rp[node], end = rp[node + 1];
    float a0 = 0.f, a1 = 0.f, a2 = 0.f, a3 = 0.f, a4 = 0.f, a5 = 0.f, a6 = 0.f, a7 = 0.f;
    for (int j = beg + half; j < end; j += 2) {
        int s = cl[j];
        uint4 v = *reinterpret_cast<const uint4*>(x + (size_t)s * 256 + l32 * 8);
        a0 += bf2f(v.x & 0xffffu); a1 += bf2f(v.x >> 16);
        a2 += bf2f(v.y & 0xffffu); a3 += bf2f(v.y >> 16);
        a4 += bf2f(v.z & 0xffffu); a5 += bf2f(v.z >> 16);
        a6 += bf2f(v.w & 0xffffu); a7 += bf2f(v.w >> 16);
    }
    a0 += __shfl_xor(a0, 32); a1 += __shfl_xor(a1, 32);
    a2 += __shfl_xor(a2, 32); a3 += __shfl_xor(a3, 32);
    a4 += __shfl_xor(a4, 32); a5 += __shfl_xor(a5, 32);
    a6 += __shfl_xor(a6, 32); a7 += __shfl_xor(a7, 32);
    if (half == 0) {
        float sc = (end > beg) ? 1.0f / (float)(end - beg) : 0.f;
        uint4 r;
        r.x = (unsigned int)f2bf(a0 * sc) | ((unsigned int)f2bf(a1 * sc) << 16);
        r.y = (unsigned int)f2bf(a2 * sc) | ((unsigned int)f2bf(a3 * sc) << 16);
        r.z = (unsigned int)f2bf(a4 * sc) | ((unsigned int)f2bf(a5 * sc) << 16);
        r.w = (unsigned int)f2bf(a6 * sc) | ((unsigned int)f2bf(a7 * sc) << 16);
        *reinterpret_cast<uint4*>(mn + (size_t)node * 256 + l32 * 8) = r;
    }
}

// ---------------- fat fused GEMM: P job (3 parts) + A job (2 parts), one dispatch ----
// 512 threads = 8 waves, 128-row x 128-col tile. grid: (mtP+mtA, 2).
template <bool LAST>
__global__ __launch_bounds__(512, 4)
void gemm_fat_k(const unsigned short* __restrict__ mW, const unsigned short* __restrict__ mC,
                const unsigned short* __restrict__ xp, const unsigned short* __restrict__ mR,
                const unsigned short* __restrict__ xa, const unsigned short* __restrict__ WT_l,
                const float* __restrict__ biasP, const float* __restrict__ biasA,
                void* __restrict__ outP, void* __restrict__ outA, int mtP) {
    __shared__ uint4 bsh4[4096];                        // 64 KiB: 128 n-rows x 256 k, swizzled
    char* bsh = reinterpret_cast<char*>(bsh4);
    const int tid = threadIdx.x;
    const int nhalf = blockIdx.y;

    const bool isP = (int)blockIdx.x < mtP;
    const int tile = isP ? blockIdx.x : blockIdx.x - mtP;
    const int parts = isP ? 3 : 2;
    const unsigned short* A0 = isP ? mW : mR;
    const unsigned short* A1 = isP ? mC : xa;
    const unsigned short* A2 = xp;
    const unsigned short* WTj = isP ? WT_l : WT_l + 3 * 65536;
    const float* bias = isP ? biasP : biasA;
    void* out = isP ? outP : outA;
    const int M = isP ? NP : NA;

    const int wid = tid >> 6;
    const int l = tid & 63;
    const int kgrp = (l >> 4) << 3;                     // 0,8,16,24
    int row = tile * 128 + (wid << 4) + (l & 15);
    int rowc = row < M ? row : M - 1;

    f32x4 acc[8];
    #pragma unroll
    for (int t = 0; t < 8; ++t) acc[t] = f32x4{0.f, 0.f, 0.f, 0.f};

    for (int p = 0; p < parts; ++p) {
        if (p) __syncthreads();
        const unsigned short* Ap = (p == 0) ? A0 : (p == 1) ? A1 : A2;
        // A-loads FIRST: latency hides under B staging + barrier
        uint4 a4[8];
        const unsigned short* Arow = Ap + (size_t)rowc * 256 + kgrp;
        #pragma unroll
        for (int s = 0; s < 8; ++s)
            a4[s] = *reinterpret_cast<const uint4*>(Arow + s * 32);
        // stage 128x256 bf16 of B, swizzled (8 chunks/thread at 512 threads)
        const unsigned short* Wt = WTj + (size_t)p * 65536 + nhalf * (128 * 256);
        #pragma unroll
        for (int i = 0; i < 8; ++i) {
            int byte = (i * 512 + tid) * 16;
            uint4 v = *reinterpret_cast<const uint4*>((const char*)Wt + byte);
            *reinterpret_cast<uint4*>(bsh + (byte ^ (((byte >> 9) & 7) << 4))) = v;
        }
        __syncthreads();

        #pragma unroll
        for (int s = 0; s < 8; ++s) {
            short8 a = __builtin_bit_cast(short8, a4[s]);
            #pragma unroll
            for (int t = 0; t < 8; ++t) {
                int nl = (t << 4) + (l & 15);
                int byte = (nl * 512 + s * 64 + kgrp * 2) ^ ((nl & 7) << 4);
                short8 bfr = __builtin_bit_cast(short8, *reinterpret_cast<const uint4*>(bsh + byte));
                acc[t] = __builtin_amdgcn_mfma_f32_16x16x32_bf16(a, bfr, acc[t], 0, 0, 0);
            }
        }
    }

    const int col = l & 15;
    const int rbase = tile * 128 + (wid << 4) + ((l >> 4) << 2);
    const int gcol0 = nhalf * 128;
    #pragma unroll
    for (int t = 0; t < 8; ++t) {
        int gc = gcol0 + (t << 4) + col;
        float badd = bias[gc];
        #pragma unroll
        for (int j = 0; j < 4; ++j) {
            int r = rbase + j;
            if (r < M) {
                float v = acc[t][j] + badd;
                if (LAST)
                    reinterpret_cast<float*>(out)[(size_t)r * 256 + gc] = v;
                else
                    reinterpret_cast<unsigned short*>(out)[(size_t)r * 256 + gc] = f2bf(v);
            }
        }
    }
}

extern "C" void kernel_launch(void* const* d_in, const int* in_sizes, int n_in,
                              void* d_out, int out_size, void* d_ws, size_t ws_size,
                              hipStream_t stream) {
    const float* x_author = (const float*)d_in[0];
    const float* x_paper  = (const float*)d_in[1];
    const int* e_w = (const int*)d_in[2];
    const int* e_r = (const int*)d_in[3];
    const int* e_c = (const int*)d_in[4];
    const float* Wl = (const float*)d_in[5];
    const float* bl = (const float*)d_in[6];
    const float* Wr = (const float*)d_in[7];
    const int E = in_sizes[2] / 2;

    float* outA = (float*)d_out;                         // [NA,256] f32
    float* outP = (float*)d_out + (size_t)NA * HH;       // [NP,256] f32

    // workspace carve (~215 MB; verified to fit in R3)
    size_t off = 0;
    auto carve = [&](size_t bytes) {
        void* p = (char*)d_ws + off;
        off += (bytes + 255) & ~(size_t)255;
        return p;
    };
    unsigned short* xa0   = (unsigned short*)carve((size_t)NA * HH * 2);
    unsigned short* xp0   = (unsigned short*)carve((size_t)NP * HH * 2);
    unsigned short* meanW = (unsigned short*)carve((size_t)NP * HH * 2);
    unsigned short* meanC = (unsigned short*)carve((size_t)NP * HH * 2);
    unsigned short* meanR = (unsigned short*)carve((size_t)NA * HH * 2);
    unsigned short* WT    = (unsigned short*)carve((size_t)15 * 65536 * 2);
    float* biasP = (float*)carve((size_t)LL * HH * 4);
    float* biasA = (float*)carve((size_t)LL * HH * 4);
    int* cnt    = (int*)carve((size_t)(2 * NP + NA) * 4);   // degree counts, reused as fill cursor
    int* rp_w   = (int*)carve((size_t)(NP + 1) * 4);
    int* rp_c   = (int*)carve((size_t)(NP + 1) * 4);
    int* rp_r   = (int*)carve((size_t)(NA + 1) * 4);
    int* part   = (int*)carve((size_t)2048 * 4);
    int* col_w  = (int*)carve((size_t)E * 4);
    int* col_c  = (int*)carve((size_t)E * 4);
    int* col_r  = (int*)carve((size_t)E * 4);
    (void)off; (void)ws_size; (void)n_in; (void)out_size;

    const size_t cntBytes = (size_t)(2 * NP + NA) * 4;
    const int egrid = (E + 255) / 256;
    const int nbP = (NP + 255) / 256, nbA = (NA + 255) / 256;
    const int mtP = (NP + 127) / 128, mtA = (NA + 127) / 128;

    // ---- one-time: weights, biases, CSR ----
    hipMemsetAsync(cnt, 0, cntBytes, stream);
    prep_w_k<<<3840, 256, 0, stream>>>(Wl, Wr, WT);
    prep_bias_k<<<3, 256, 0, stream>>>(bl, biasP, biasA);
    count3_k<<<3 * egrid, 256, 0, stream>>>(e_w + E, e_c + E, e_r + E, cnt, E, egrid);
    scanA_k<<<2 * nbP + nbA, 256, 0, stream>>>(cnt, part, nbP, nbA);
    scanB_k<<<3, 512, 0, stream>>>(part, nbP, nbA);
    scanC_k<<<2 * nbP + nbA, 256, 0, stream>>>(cnt, part, rp_w, rp_c, rp_r, nbP, nbA);
    hipMemsetAsync(cnt, 0, cntBytes, stream);            // re-zero -> fill cursor
    fill3_k<<<3 * egrid, 256, 0, stream>>>(e_w, e_c, e_r, rp_w, rp_c, rp_r,
                                           cnt, col_w, col_c, col_r, E, egrid);

    cast_bf16_k<<<(NA * HH / 8 + 255) / 256, 256, 0, stream>>>(x_author, xa0, NA * HH / 8);
    cast_bf16_k<<<(NP * HH / 8 + 255) / 256, 256, 0, stream>>>(x_paper, xp0, NP * HH / 8);

    // bf16 ping set inside d_out (overwritten by f32 at l=2)
    unsigned short* xa1 = (unsigned short*)d_out;
    unsigned short* xp1 = xa1 + (size_t)NA * HH;

    unsigned short* xa_cur = xa0; unsigned short* xp_cur = xp0;
    unsigned short* xa_nxt = xa1; unsigned short* xp_nxt = xp1;

    const int aggGrid = 2 * GP + GA;

    for (int l = 0; l < LL; ++l) {
        const unsigned short* WT_l = WT + (size_t)l * 5 * 65536;
        agg_fused_k<<<aggGrid, 256, 0, stream>>>(xa_cur, xp_cur, rp_w, col_w,
                                                 rp_c, col_c, rp_r, col_r,
                                                 meanW, meanC, meanR);
        if (l < LL - 1) {
            gemm_fat_k<false><<<dim3(mtP + mtA, 2), 512, 0, stream>>>(
                meanW, meanC, xp_cur, meanR, xa_cur, WT_l,
                biasP + l * 256, biasA + l * 256, xp_nxt, xa_nxt, mtP);
            unsigned short* t;
            t = xa_cur; xa_cur = xa_nxt; xa_nxt = t;
            t = xp_cur; xp_cur = xp_nxt; xp_nxt = t;
        } else {
            gemm_fat_k<true><<<dim3(mtP + mtA, 2), 512, 0, stream>>>(
                meanW, meanC, xp_cur, meanR, xa_cur, WT_l,
                biasP + l * 256, biasA + l * 256, outP, outA, mtP);
        }
    }
}